// Round 3
// baseline (1087.184 us; speedup 1.0000x reference)
//
#include <hip/hip_runtime.h>

// 2-layer LSTM, B=1024 T=512 D=1 H=64.
// 128 blocks x 256 threads: blocks 0-63 = layer0 producers (16 batches each),
// blocks 64-127 = layer1 consumers. h0 stream crosses blocks through a ring
// in d_ws (f16, device-scope cache-bypassing atomics) with per-step tag flags.
// Pointwise uses fused-rcp sigmoid/tanh: 5 exp2 + 3 rcp per element.

typedef _Float16 f16x8 __attribute__((ext_vector_type(8)));
typedef float f32x4 __attribute__((ext_vector_type(4)));
typedef unsigned long long u64;

#define TSTEPS 512
#define MB 16
#define HPAD 72
#define NGRP 64
#define L2E 1.44269504088896340736f

__device__ __forceinline__ float lstm_point(float ai, float af, float ag, float ao,
                                            float& c) {
    // ai,af,ao pre-scaled by -log2e ; ag by +2log2e
    const float p  = __builtin_amdgcn_exp2f(ai);
    const float s_ = __builtin_amdgcn_exp2f(af);
    const float r_ = __builtin_amdgcn_exp2f(ag);
    const float v  = __builtin_amdgcn_exp2f(ao);
    const float f  = __builtin_amdgcn_rcpf(1.f + s_);
    const float ig = (r_ - 1.f) * __builtin_amdgcn_rcpf((1.f + p) * (1.f + r_));
    const float cc = __builtin_fmaf(f, c, ig);
    c = cc;
    const float w  = __builtin_amdgcn_exp2f(cc * (2.f * L2E));
    return (w - 1.f) * __builtin_amdgcn_rcpf((1.f + v) * (1.f + w));
}

__global__ __launch_bounds__(256) void lstm2_pipe(
    const float* __restrict__ x,
    const float* __restrict__ W_ih0, const float* __restrict__ W_hh0,
    const float* __restrict__ b_ih0, const float* __restrict__ b_hh0,
    const float* __restrict__ W_ih1, const float* __restrict__ W_hh1,
    const float* __restrict__ b_ih1, const float* __restrict__ b_hh1,
    const float* __restrict__ W_fc,  const float* __restrict__ b_fc,
    float* __restrict__ out,
    unsigned* __restrict__ flags, unsigned* __restrict__ prog,
    unsigned short* __restrict__ data, int R, int Rmask)
{
    __shared__ _Float16 hs[2][MB * HPAD];   // own layer's h double-buffer
    __shared__ float    xlds[64 * 20];      // producer only

    const int tid  = (int)threadIdx.x;
    const int lane = tid & 63;
    const int w    = tid >> 6;          // wave 0..3
    const int c    = lane & 15;
    const int quad = lane >> 4;
    const int j    = (w << 4) | c;
    const bool producer = ((int)blockIdx.x < NGRP);
    const int g    = producer ? (int)blockIdx.x : (int)blockIdx.x - NGRP;
    const int b0   = g * MB;

    // ---- register weight fragments ----
    float biasc[4], wih0c[4];
    f16x8 bf[4][4];
    if (producer) {
#pragma unroll
        for (int gg = 0; gg < 4; ++gg) {
            const int n = j + 64 * gg;
            const float sg = (gg == 2) ? (2.0f * L2E) : (-L2E);
            biasc[gg] = sg * (b_ih0[n] + b_hh0[n]);
            wih0c[gg] = sg * W_ih0[n];               // D == 1
#pragma unroll
            for (int kb = 0; kb < 2; ++kb) {
                const float* p = W_hh0 + n * 64 + kb * 32 + quad * 8;
#pragma unroll
                for (int q = 0; q < 8; ++q) bf[gg][kb][q] = (_Float16)(p[q] * sg);
            }
        }
    } else {
#pragma unroll
        for (int gg = 0; gg < 4; ++gg) {
            const int n = j + 64 * gg;
            const float sg = (gg == 2) ? (2.0f * L2E) : (-L2E);
            biasc[gg] = sg * (b_ih1[n] + b_hh1[n]);
#pragma unroll
            for (int kb = 0; kb < 4; ++kb) {
                const int kk = kb * 32 + quad * 8;
                const float* p = (kk < 64) ? (W_ih1 + n * 64 + kk)
                                           : (W_hh1 + n * 64 + (kk - 64));
#pragma unroll
                for (int q = 0; q < 8; ++q) bf[gg][kb][q] = (_Float16)(p[q] * sg);
            }
        }
    }

    for (int i = tid; i < MB * HPAD; i += 256) {
        hs[0][i] = (_Float16)0.f; hs[1][i] = (_Float16)0.f;
    }

    float cst[4] = {0.f, 0.f, 0.f, 0.f};

    if (producer) {
        unsigned short hbits[4] = {0, 0, 0, 0};
        int last_prog = -1;
        for (int t = 0; t < TSTEPS; ++t) {
            if ((t & 63) == 0) {
                __syncthreads();
                const int m = tid & 15, ii = tid >> 4;
#pragma unroll
                for (int p4 = 0; p4 < 4; ++p4) {
                    const int i = ii + 16 * p4;
                    xlds[i * 20 + m] = x[(b0 + m) * TSTEPS + t + i];
                }
                __syncthreads();
            }
            // delayed publish of h0(t-1): fire-and-forget stores, drain at barrier
            if (t > 0) {
                const int pt = t - 1;
                const int need = pt - R + 1;
                if (need > last_prog) {
                    while (true) {
                        unsigned pv = __hip_atomic_load(prog + g, __ATOMIC_RELAXED,
                                                        __HIP_MEMORY_SCOPE_AGENT);
                        int pp = ((pv >> 24) == 0x7Au) ? (int)(pv & 0xFFFFFFu) : -1;
                        if (pp >= need) { last_prog = pp; break; }
                        __builtin_amdgcn_s_sleep(8);
                    }
                }
                unsigned short* dst = data + ((size_t)(g * R + (pt & Rmask)) << 10);
#pragma unroll
                for (int r = 0; r < 4; ++r)
                    __hip_atomic_store(dst + (quad * 4 + r) * 64 + j, hbits[r],
                                       __ATOMIC_RELAXED, __HIP_MEMORY_SCOPE_AGENT);
            }

            const int pr = (t + 1) & 1, pw = t & 1;
            const f32x4 xv = *(const f32x4*)&xlds[(t & 63) * 20 + quad * 4];
            f32x4 acc[4];
#pragma unroll
            for (int gg = 0; gg < 4; ++gg)
#pragma unroll
                for (int r = 0; r < 4; ++r) acc[gg][r] = biasc[gg] + xv[r] * wih0c[gg];

            const f16x8 a0 = *(const f16x8*)&hs[pr][c * HPAD + quad * 8];
            const f16x8 a1 = *(const f16x8*)&hs[pr][c * HPAD + 32 + quad * 8];
#pragma unroll
            for (int gg = 0; gg < 4; ++gg) {
                acc[gg] = __builtin_amdgcn_mfma_f32_16x16x32_f16(a0, bf[gg][0], acc[gg], 0, 0, 0);
                acc[gg] = __builtin_amdgcn_mfma_f32_16x16x32_f16(a1, bf[gg][1], acc[gg], 0, 0, 0);
            }
#pragma unroll
            for (int r = 0; r < 4; ++r) {
                const float hv = lstm_point(acc[0][r], acc[1][r], acc[2][r], acc[3][r], cst[r]);
                const _Float16 h16 = (_Float16)hv;
                hs[pw][(quad * 4 + r) * HPAD + j] = h16;
                hbits[r] = __builtin_bit_cast(unsigned short, h16);
            }
            __syncthreads();   // h0(t) in LDS; h0(t-1) global stores drained
            if (tid == 0 && t > 0)
                __hip_atomic_store(flags + g * R + ((t - 1) & Rmask),
                                   0x51000000u | (unsigned)(t - 1),
                                   __ATOMIC_RELAXED, __HIP_MEMORY_SCOPE_AGENT);
        }
        // final step publish
        {
            const int pt = TSTEPS - 1;
            unsigned short* dst = data + ((size_t)(g * R + (pt & Rmask)) << 10);
#pragma unroll
            for (int r = 0; r < 4; ++r)
                __hip_atomic_store(dst + (quad * 4 + r) * 64 + j, hbits[r],
                                   __ATOMIC_RELAXED, __HIP_MEMORY_SCOPE_AGENT);
            __syncthreads();
            if (tid == 0)
                __hip_atomic_store(flags + g * R + (pt & Rmask),
                                   0x51000000u | (unsigned)pt,
                                   __ATOMIC_RELAXED, __HIP_MEMORY_SCOPE_AGENT);
        }
        if (tid < 16) {
            float s = b_fc[0];
            for (int jj = 0; jj < 64; ++jj) s += (float)hs[1][tid * HPAD + jj] * W_fc[jj];
            out[b0 + tid] = s;
        }
    } else {
        // ================= consumer: layer 1 =================
        u64 cur[4], nxt[4];
        {   // blocking acquire of h0(0)
            unsigned* fp = flags + g * R + 0;
            while (__hip_atomic_load(fp, __ATOMIC_RELAXED, __HIP_MEMORY_SCOPE_AGENT)
                   != 0x51000000u) {
                __builtin_amdgcn_s_sleep(2);
            }
            __builtin_amdgcn_fence(__ATOMIC_ACQUIRE, "agent");
            const u64* src = (const u64*)(data + ((size_t)(g * R) << 10));
            const int bi = c * 16 + quad * 2;
            cur[0] = __hip_atomic_load(src + bi,     __ATOMIC_RELAXED, __HIP_MEMORY_SCOPE_AGENT);
            cur[1] = __hip_atomic_load(src + bi + 1, __ATOMIC_RELAXED, __HIP_MEMORY_SCOPE_AGENT);
            cur[2] = __hip_atomic_load(src + bi + 8, __ATOMIC_RELAXED, __HIP_MEMORY_SCOPE_AGENT);
            cur[3] = __hip_atomic_load(src + bi + 9, __ATOMIC_RELAXED, __HIP_MEMORY_SCOPE_AGENT);
        }
        for (int s = 0; s < TSTEPS; ++s) {
            if (tid == 0 && (s & 15) == 15)
                __hip_atomic_store(prog + g, 0x7A000000u | (unsigned)s,
                                   __ATOMIC_RELAXED, __HIP_MEMORY_SCOPE_AGENT);
            if (s < TSTEPS - 1) {   // early poll + prefetch h0(s+1); overlaps compute
                const unsigned tag = 0x51000000u | (unsigned)(s + 1);
                unsigned* fp = flags + g * R + ((s + 1) & Rmask);
                while (__hip_atomic_load(fp, __ATOMIC_RELAXED, __HIP_MEMORY_SCOPE_AGENT) != tag) {
                    __builtin_amdgcn_s_sleep(2);
                }
                __builtin_amdgcn_fence(__ATOMIC_ACQUIRE, "agent");
                const u64* src = (const u64*)(data + ((size_t)(g * R + ((s + 1) & Rmask)) << 10));
                const int bi = c * 16 + quad * 2;
                nxt[0] = __hip_atomic_load(src + bi,     __ATOMIC_RELAXED, __HIP_MEMORY_SCOPE_AGENT);
                nxt[1] = __hip_atomic_load(src + bi + 1, __ATOMIC_RELAXED, __HIP_MEMORY_SCOPE_AGENT);
                nxt[2] = __hip_atomic_load(src + bi + 8, __ATOMIC_RELAXED, __HIP_MEMORY_SCOPE_AGENT);
                nxt[3] = __hip_atomic_load(src + bi + 9, __ATOMIC_RELAXED, __HIP_MEMORY_SCOPE_AGENT);
            }
            const int pr = (s + 1) & 1, pw = s & 1;
            f32x4 acc[4];
#pragma unroll
            for (int gg = 0; gg < 4; ++gg)
#pragma unroll
                for (int r = 0; r < 4; ++r) acc[gg][r] = biasc[gg];

            union { u64 q[2]; f16x8 v; } u0, u1;
            u0.q[0] = cur[0]; u0.q[1] = cur[1];
            u1.q[0] = cur[2]; u1.q[1] = cur[3];
            const f16x8 a10 = u0.v;                 // h0(s) k 0..31
            const f16x8 a11 = u1.v;                 // h0(s) k 32..63
            const f16x8 a12 = *(const f16x8*)&hs[pr][c * HPAD + quad * 8];
            const f16x8 a13 = *(const f16x8*)&hs[pr][c * HPAD + 32 + quad * 8];
#pragma unroll
            for (int gg = 0; gg < 4; ++gg) {
                acc[gg] = __builtin_amdgcn_mfma_f32_16x16x32_f16(a12, bf[gg][2], acc[gg], 0, 0, 0);
                acc[gg] = __builtin_amdgcn_mfma_f32_16x16x32_f16(a13, bf[gg][3], acc[gg], 0, 0, 0);
                acc[gg] = __builtin_amdgcn_mfma_f32_16x16x32_f16(a10, bf[gg][0], acc[gg], 0, 0, 0);
                acc[gg] = __builtin_amdgcn_mfma_f32_16x16x32_f16(a11, bf[gg][1], acc[gg], 0, 0, 0);
            }
#pragma unroll
            for (int r = 0; r < 4; ++r) {
                const float hv = lstm_point(acc[0][r], acc[1][r], acc[2][r], acc[3][r], cst[r]);
                hs[pw][(quad * 4 + r) * HPAD + j] = (_Float16)hv;
            }
            __syncthreads();
            cur[0] = nxt[0]; cur[1] = nxt[1]; cur[2] = nxt[2]; cur[3] = nxt[3];
        }
        if (tid < 16) {
            float s = b_fc[0];
            for (int jj = 0; jj < 64; ++jj) s += (float)hs[1][tid * HPAD + jj] * W_fc[jj];
            out[1024 + b0 + tid] = s;
        }
    }
}

extern "C" void kernel_launch(void* const* d_in, const int* in_sizes, int n_in,
                              void* d_out, int out_size, void* d_ws, size_t ws_size,
                              hipStream_t stream) {
    (void)in_sizes; (void)n_in; (void)out_size;
    // ring depth: largest pow2 <= 512 fitting in ws
    int R = 512;
    while (R > 4) {
        size_t need = (size_t)NGRP * R * 4 + 4096 + (size_t)NGRP * R * 2048;
        if (need <= ws_size) break;
        R >>= 1;
    }
    unsigned* flags = (unsigned*)d_ws;
    unsigned* prog  = flags + (size_t)NGRP * R;
    size_t data_off = ((size_t)NGRP * R * 4 + 256 + 4095) & ~(size_t)4095;
    unsigned short* data = (unsigned short*)((char*)d_ws + data_off);

    lstm2_pipe<<<128, 256, 0, stream>>>(
        (const float*)d_in[0],
        (const float*)d_in[1], (const float*)d_in[2],
        (const float*)d_in[3], (const float*)d_in[4],
        (const float*)d_in[5], (const float*)d_in[6],
        (const float*)d_in[7], (const float*)d_in[8],
        (const float*)d_in[9], (const float*)d_in[10],
        (float*)d_out, flags, prog, data, R, R - 1);
}

// Round 4
// 458.288 us; speedup vs baseline: 2.3723x; 2.3723x over previous
//
#include <hip/hip_runtime.h>

// 2-layer LSTM, B=1024 T=512 D=1 H=64. 64 blocks x 512 threads.
// Waves 0-3 (group A) = layer0 step t; waves 4-7 (group B) = layer1 step t-1.
// One __syncthreads per iteration, parity double-buffers for h0/h1.
// Weights in registers as f16 MFMA B-frags. Fused pointwise: 5 exp2 + 3 rcp.
// h LDS layout: 16 rows x 64 cols f16, 16B-block XOR swizzle (block ^= row&7)
// -> conflict-free b128 reads and 2-way-max writes, no padding.

typedef _Float16 f16x8 __attribute__((ext_vector_type(8)));
typedef float f32x4 __attribute__((ext_vector_type(4)));

#define TSTEPS 512
#define MB 16
#define L2E 1.44269504088896340736f

__device__ __forceinline__ int hidx(int row, int j) {
    // swizzled index into a 16x64 half tile
    return row * 64 + ((((j >> 3) ^ (row & 7)) << 3) | (j & 7));
}

__device__ __forceinline__ float lstm_point(float ai, float af, float ag, float ao,
                                            float& c) {
    // ai,af,ao pre-scaled by -log2e ; ag by +2log2e
    const float p  = __builtin_amdgcn_exp2f(ai);
    const float s_ = __builtin_amdgcn_exp2f(af);
    const float r_ = __builtin_amdgcn_exp2f(ag);
    const float v  = __builtin_amdgcn_exp2f(ao);
    const float f  = __builtin_amdgcn_rcpf(1.f + s_);
    const float ig = (r_ - 1.f) * __builtin_amdgcn_rcpf((1.f + p) * (1.f + r_));
    const float cc = __builtin_fmaf(f, c, ig);
    c = cc;
    const float w  = __builtin_amdgcn_exp2f(cc * (2.f * L2E));
    return (w - 1.f) * __builtin_amdgcn_rcpf((1.f + v) * (1.f + w));
}

__global__ __launch_bounds__(512) void lstm2_kernel(
    const float* __restrict__ x,
    const float* __restrict__ W_ih0, const float* __restrict__ W_hh0,
    const float* __restrict__ b_ih0, const float* __restrict__ b_hh0,
    const float* __restrict__ W_ih1, const float* __restrict__ W_hh1,
    const float* __restrict__ b_ih1, const float* __restrict__ b_hh1,
    const float* __restrict__ W_fc,  const float* __restrict__ b_fc,
    float* __restrict__ out)
{
    __shared__ _Float16 h0s[2][MB * 64];
    __shared__ _Float16 h1s[2][MB * 64];
    __shared__ float    xlds[64 * 20];       // [step-in-chunk][m], pad 20

    const int tid  = (int)threadIdx.x;
    const int lane = tid & 63;
    const int w8   = tid >> 6;          // wave 0..7
    const bool gB  = (w8 >= 4);         // group B = layer1
    const int w    = w8 & 3;            // wave within group
    const int c    = lane & 15;
    const int quad = lane >> 4;
    const int j    = (w << 4) | c;      // hidden unit owned by this lane
    const int b0   = (int)blockIdx.x * MB;

    // swizzled, loop-invariant addresses
    const int rdA0 = hidx(c, quad * 8);             // k-block quad
    const int rdA1 = hidx(c, quad * 8 + 32);        // k-block quad+4
    int wrH[4];
#pragma unroll
    for (int r = 0; r < 4; ++r) wrH[r] = hidx(quad * 4 + r, j);

    // ---- per-group register weight fragments ----
    float biasc[4], wih0c[4];
    f16x8 bf[4][4];   // A uses [g][0..1] (W_hh0); B uses [g][0..3] ([W_ih1|W_hh1])

    if (!gB) {
#pragma unroll
        for (int g = 0; g < 4; ++g) {
            const int n = j + 64 * g;
            const float sg = (g == 2) ? (2.0f * L2E) : (-L2E);
            biasc[g] = sg * (b_ih0[n] + b_hh0[n]);
            wih0c[g] = sg * W_ih0[n];                 // D == 1
#pragma unroll
            for (int kb = 0; kb < 2; ++kb) {
                const float* p = W_hh0 + n * 64 + kb * 32 + quad * 8;
#pragma unroll
                for (int q = 0; q < 8; ++q) bf[g][kb][q] = (_Float16)(p[q] * sg);
            }
        }
    } else {
#pragma unroll
        for (int g = 0; g < 4; ++g) {
            const int n = j + 64 * g;
            const float sg = (g == 2) ? (2.0f * L2E) : (-L2E);
            biasc[g] = sg * (b_ih1[n] + b_hh1[n]);
#pragma unroll
            for (int kb = 0; kb < 4; ++kb) {
                const int kk = kb * 32 + quad * 8;
                const float* p = (kk < 64) ? (W_ih1 + n * 64 + kk)
                                           : (W_hh1 + n * 64 + (kk - 64));
#pragma unroll
                for (int q = 0; q < 8; ++q) bf[g][kb][q] = (_Float16)(p[q] * sg);
            }
        }
    }

    // zero-init h buffers (h(-1) = 0 in both parities)
    for (int i = tid; i < MB * 64; i += 512) {
        h0s[0][i] = (_Float16)0.f; h0s[1][i] = (_Float16)0.f;
        h1s[0][i] = (_Float16)0.f; h1s[1][i] = (_Float16)0.f;
    }

    float cst[4] = {0.f, 0.f, 0.f, 0.f};   // c0 for group A waves, c1 for group B

    for (int t = 0; t <= TSTEPS; ++t) {
        if (t < TSTEPS && (t & 63) == 0) {
            __syncthreads();                 // prior chunk's xlds reads done
            const int m  = tid >> 5;         // 0..15
            const int ii = tid & 31;         // 0..31 (coalesced over x)
            xlds[ii * 20 + m]        = x[(b0 + m) * TSTEPS + t + ii];
            xlds[(ii + 32) * 20 + m] = x[(b0 + m) * TSTEPS + t + ii + 32];
            __syncthreads();
        }

        if (!gB) {
            // ===== group A: layer0, compute h0(t) from h0(t-1), x(t) =====
            if (t < TSTEPS) {
                const int pr = (t + 1) & 1, pw = t & 1;
                const f32x4 xv = *(const f32x4*)&xlds[(t & 63) * 20 + quad * 4];
                f32x4 acc[4];
#pragma unroll
                for (int g = 0; g < 4; ++g)
#pragma unroll
                    for (int r = 0; r < 4; ++r) acc[g][r] = biasc[g] + xv[r] * wih0c[g];

                const f16x8 a0 = *(const f16x8*)&h0s[pr][rdA0];
                const f16x8 a1 = *(const f16x8*)&h0s[pr][rdA1];
#pragma unroll
                for (int g = 0; g < 4; ++g) {
                    acc[g] = __builtin_amdgcn_mfma_f32_16x16x32_f16(a0, bf[g][0], acc[g], 0, 0, 0);
                    acc[g] = __builtin_amdgcn_mfma_f32_16x16x32_f16(a1, bf[g][1], acc[g], 0, 0, 0);
                }
#pragma unroll
                for (int r = 0; r < 4; ++r) {
                    const float hv = lstm_point(acc[0][r], acc[1][r], acc[2][r], acc[3][r], cst[r]);
                    h0s[pw][wrH[r]] = (_Float16)hv;
                }
            }
        } else {
            // ===== group B: layer1, compute h1(s), s = t-1, from h0(s), h1(s-1) =====
            if (t > 0) {
                const int s = t - 1;
                const int prh0 = s & 1;          // h0(s) written by A at iter s
                const int prh1 = (s + 1) & 1;    // h1(s-1)
                const int pwh1 = s & 1;
                f32x4 acc[4];
#pragma unroll
                for (int g = 0; g < 4; ++g)
#pragma unroll
                    for (int r = 0; r < 4; ++r) acc[g][r] = biasc[g];

                const f16x8 a10 = *(const f16x8*)&h0s[prh0][rdA0];
                const f16x8 a11 = *(const f16x8*)&h0s[prh0][rdA1];
                const f16x8 a12 = *(const f16x8*)&h1s[prh1][rdA0];
                const f16x8 a13 = *(const f16x8*)&h1s[prh1][rdA1];
#pragma unroll
                for (int g = 0; g < 4; ++g) {
                    acc[g] = __builtin_amdgcn_mfma_f32_16x16x32_f16(a10, bf[g][0], acc[g], 0, 0, 0);
                    acc[g] = __builtin_amdgcn_mfma_f32_16x16x32_f16(a11, bf[g][1], acc[g], 0, 0, 0);
                    acc[g] = __builtin_amdgcn_mfma_f32_16x16x32_f16(a12, bf[g][2], acc[g], 0, 0, 0);
                    acc[g] = __builtin_amdgcn_mfma_f32_16x16x32_f16(a13, bf[g][3], acc[g], 0, 0, 0);
                }
#pragma unroll
                for (int r = 0; r < 4; ++r) {
                    const float hv = lstm_point(acc[0][r], acc[1][r], acc[2][r], acc[3][r], cst[r]);
                    h1s[pwh1][wrH[r]] = (_Float16)hv;
                }
            }
        }
        __syncthreads();
    }

    // ---- epilogue: final states. h0(511) in parity 1, h1(511) in parity 1.
    if (tid < 32) {
        const int which = tid >> 4, m = tid & 15;
        const _Float16* hb = which ? &h1s[1][0] : &h0s[1][0];
        float s = b_fc[0];
        for (int jj = 0; jj < 64; ++jj) s += (float)hb[hidx(m, jj)] * W_fc[jj];
        out[which * 1024 + b0 + m] = s;
    }
}

extern "C" void kernel_launch(void* const* d_in, const int* in_sizes, int n_in,
                              void* d_out, int out_size, void* d_ws, size_t ws_size,
                              hipStream_t stream) {
    (void)in_sizes; (void)n_in; (void)d_ws; (void)ws_size; (void)out_size;
    lstm2_kernel<<<64, 512, 0, stream>>>(
        (const float*)d_in[0],
        (const float*)d_in[1], (const float*)d_in[2],
        (const float*)d_in[3], (const float*)d_in[4],
        (const float*)d_in[5], (const float*)d_in[6],
        (const float*)d_in[7], (const float*)d_in[8],
        (const float*)d_in[9], (const float*)d_in[10],
        (float*)d_out);
}

// Round 5
// 432.336 us; speedup vs baseline: 2.5147x; 1.0600x over previous
//
#include <hip/hip_runtime.h>

// 2-layer LSTM, B=1024 T=512 D=1 H=64. 256 blocks x 512 threads (all 256 CUs).
// MB=4 batches per block. Waves 0-3 = layer0 step t; waves 4-7 = layer1 step t-1.
// MFMA M=16 with rows 4-15 unused (zero). Post-MFMA: gates live in quad-0 lanes;
// redistribute via 16 ds_bpermute (__shfl) so each lane does 1 lstm_point, full exec.
// Split-accumulator MFMA halves the dependent-MFMA chain depth.
// One __syncthreads per step; h tiles XOR-swizzled, parity double-buffered.

typedef _Float16 f16x8 __attribute__((ext_vector_type(8)));
typedef float f32x4 __attribute__((ext_vector_type(4)));

#define TSTEPS 512
#define MB 4
#define L2E 1.44269504088896340736f

__device__ __forceinline__ int hidx(int row, int j) {
    // swizzled index into a 16x64 half tile
    return row * 64 + ((((j >> 3) ^ (row & 7)) << 3) | (j & 7));
}

__device__ __forceinline__ float lstm_point(float ai, float af, float ag, float ao,
                                            float& c) {
    // ai,af,ao pre-scaled by -log2e ; ag by +2log2e
    const float p  = __builtin_amdgcn_exp2f(ai);
    const float s_ = __builtin_amdgcn_exp2f(af);
    const float r_ = __builtin_amdgcn_exp2f(ag);
    const float v  = __builtin_amdgcn_exp2f(ao);
    const float f  = __builtin_amdgcn_rcpf(1.f + s_);
    const float ig = (r_ - 1.f) * __builtin_amdgcn_rcpf((1.f + p) * (1.f + r_));
    const float cc = __builtin_fmaf(f, c, ig);
    c = cc;
    const float w  = __builtin_amdgcn_exp2f(cc * (2.f * L2E));
    return (w - 1.f) * __builtin_amdgcn_rcpf((1.f + v) * (1.f + w));
}

__global__ __launch_bounds__(512) void lstm2_kernel(
    const float* __restrict__ x,
    const float* __restrict__ W_ih0, const float* __restrict__ W_hh0,
    const float* __restrict__ b_ih0, const float* __restrict__ b_hh0,
    const float* __restrict__ W_ih1, const float* __restrict__ W_hh1,
    const float* __restrict__ b_ih1, const float* __restrict__ b_hh1,
    const float* __restrict__ W_fc,  const float* __restrict__ b_fc,
    float* __restrict__ out)
{
    __shared__ _Float16 h0s[2][16 * 64];
    __shared__ _Float16 h1s[2][16 * 64];
    __shared__ float    xlds[64 * 8];        // [step-in-chunk][row 0..3], stride 8

    const int tid  = (int)threadIdx.x;
    const int lane = tid & 63;
    const int w8   = tid >> 6;          // wave 0..7
    const bool gB  = (w8 >= 4);         // group B = layer1
    const int w    = w8 & 3;            // wave within group
    const int c    = lane & 15;
    const int quad = lane >> 4;
    const int j    = (w << 4) | c;      // hidden unit owned by this lane
    const int b0   = (int)blockIdx.x * MB;

    const int rdA0 = hidx(c, quad * 8);
    const int rdA1 = hidx(c, quad * 8 + 32);
    const int wrH  = hidx(quad, j);     // this lane's point: (batch=quad, unit=j)

    // ---- per-group register weight fragments ----
    float biasc[4], wih0c[4];
    f16x8 bf[4][4];   // A uses [g][0..1] (W_hh0); B uses [g][0..3] ([W_ih1|W_hh1])

    if (!gB) {
#pragma unroll
        for (int g = 0; g < 4; ++g) {
            const int n = j + 64 * g;
            const float sg = (g == 2) ? (2.0f * L2E) : (-L2E);
            biasc[g] = sg * (b_ih0[n] + b_hh0[n]);
            wih0c[g] = sg * W_ih0[n];                 // D == 1
#pragma unroll
            for (int kb = 0; kb < 2; ++kb) {
                const float* p = W_hh0 + n * 64 + kb * 32 + quad * 8;
#pragma unroll
                for (int q = 0; q < 8; ++q) bf[g][kb][q] = (_Float16)(p[q] * sg);
            }
        }
    } else {
#pragma unroll
        for (int g = 0; g < 4; ++g) {
            const int n = j + 64 * g;
            const float sg = (g == 2) ? (2.0f * L2E) : (-L2E);
            biasc[g] = sg * (b_ih1[n] + b_hh1[n]);
#pragma unroll
            for (int kb = 0; kb < 4; ++kb) {
                const int kk = kb * 32 + quad * 8;
                const float* p = (kk < 64) ? (W_ih1 + n * 64 + kk)
                                           : (W_hh1 + n * 64 + (kk - 64));
#pragma unroll
                for (int q = 0; q < 8; ++q) bf[g][kb][q] = (_Float16)(p[q] * sg);
            }
        }
    }

    // zero-init h buffers (rows 4-15 stay zero forever)
    for (int i = tid; i < 16 * 64; i += 512) {
        h0s[0][i] = (_Float16)0.f; h0s[1][i] = (_Float16)0.f;
        h1s[0][i] = (_Float16)0.f; h1s[1][i] = (_Float16)0.f;
    }

    float cst = 0.f;           // cell state for (batch=quad, unit=j)
    const f32x4 zf4 = {0.f, 0.f, 0.f, 0.f};

    for (int t = 0; t <= TSTEPS; ++t) {
        if (t < TSTEPS && (t & 63) == 0) {
            __syncthreads();                 // prior chunk's xlds reads done
            if (tid < 256) {
                const int i = tid >> 2, m = tid & 3;
                xlds[i * 8 + m] = x[(b0 + m) * TSTEPS + t + i];
            }
            __syncthreads();
        }

        if (!gB) {
            // ===== layer0: h0(t) from h0(t-1), x(t) =====
            if (t < TSTEPS) {
                const int pr = (t + 1) & 1, pw = t & 1;
                const f32x4 xv = *(const f32x4*)&xlds[(t & 63) * 8];
                f32x4 accP[4], accQ[4];
#pragma unroll
                for (int g = 0; g < 4; ++g)
#pragma unroll
                    for (int r = 0; r < 4; ++r) accP[g][r] = biasc[g] + xv[r] * wih0c[g];

                const f16x8 a0 = *(const f16x8*)&h0s[pr][rdA0];
                const f16x8 a1 = *(const f16x8*)&h0s[pr][rdA1];
#pragma unroll
                for (int g = 0; g < 4; ++g) {
                    accP[g] = __builtin_amdgcn_mfma_f32_16x16x32_f16(a0, bf[g][0], accP[g], 0, 0, 0);
                    accQ[g] = __builtin_amdgcn_mfma_f32_16x16x32_f16(a1, bf[g][1], zf4,     0, 0, 0);
                }
                float gate[4];
#pragma unroll
                for (int g = 0; g < 4; ++g) {
                    const f32x4 a = accP[g] + accQ[g];
                    const float t0 = __shfl(a[0], c, 64);
                    const float t1 = __shfl(a[1], c, 64);
                    const float t2 = __shfl(a[2], c, 64);
                    const float t3 = __shfl(a[3], c, 64);
                    gate[g] = (quad < 2) ? (quad == 0 ? t0 : t1)
                                         : (quad == 2 ? t2 : t3);
                }
                const float hv = lstm_point(gate[0], gate[1], gate[2], gate[3], cst);
                h0s[pw][wrH] = (_Float16)hv;
            }
        } else {
            // ===== layer1: h1(s), s=t-1, from h0(s), h1(s-1) =====
            if (t > 0) {
                const int s = t - 1;
                const int prh0 = s & 1;
                const int prh1 = (s + 1) & 1;
                const int pwh1 = s & 1;
                f32x4 accP[4], accQ[4];
#pragma unroll
                for (int g = 0; g < 4; ++g)
#pragma unroll
                    for (int r = 0; r < 4; ++r) accP[g][r] = biasc[g];

                const f16x8 a10 = *(const f16x8*)&h0s[prh0][rdA0];
                const f16x8 a11 = *(const f16x8*)&h0s[prh0][rdA1];
                const f16x8 a12 = *(const f16x8*)&h1s[prh1][rdA0];
                const f16x8 a13 = *(const f16x8*)&h1s[prh1][rdA1];
#pragma unroll
                for (int g = 0; g < 4; ++g) {
                    accP[g] = __builtin_amdgcn_mfma_f32_16x16x32_f16(a10, bf[g][0], accP[g], 0, 0, 0);
                    accP[g] = __builtin_amdgcn_mfma_f32_16x16x32_f16(a11, bf[g][1], accP[g], 0, 0, 0);
                    accQ[g] = __builtin_amdgcn_mfma_f32_16x16x32_f16(a12, bf[g][2], zf4,     0, 0, 0);
                    accQ[g] = __builtin_amdgcn_mfma_f32_16x16x32_f16(a13, bf[g][3], accQ[g], 0, 0, 0);
                }
                float gate[4];
#pragma unroll
                for (int g = 0; g < 4; ++g) {
                    const f32x4 a = accP[g] + accQ[g];
                    const float t0 = __shfl(a[0], c, 64);
                    const float t1 = __shfl(a[1], c, 64);
                    const float t2 = __shfl(a[2], c, 64);
                    const float t3 = __shfl(a[3], c, 64);
                    gate[g] = (quad < 2) ? (quad == 0 ? t0 : t1)
                                         : (quad == 2 ? t2 : t3);
                }
                const float hv = lstm_point(gate[0], gate[1], gate[2], gate[3], cst);
                h1s[pwh1][wrH] = (_Float16)hv;
            }
        }
        __syncthreads();
    }

    // ---- epilogue: h0(511), h1(511) both in parity 1 ----
    if (tid < 8) {
        const int which = tid >> 2, m = tid & 3;
        const _Float16* hb = which ? &h1s[1][0] : &h0s[1][0];
        float s = b_fc[0];
        for (int jj = 0; jj < 64; ++jj) s += (float)hb[hidx(m, jj)] * W_fc[jj];
        out[which * 1024 + b0 + m] = s;
    }
}

extern "C" void kernel_launch(void* const* d_in, const int* in_sizes, int n_in,
                              void* d_out, int out_size, void* d_ws, size_t ws_size,
                              hipStream_t stream) {
    (void)in_sizes; (void)n_in; (void)d_ws; (void)ws_size; (void)out_size;
    lstm2_kernel<<<256, 512, 0, stream>>>(
        (const float*)d_in[0],
        (const float*)d_in[1], (const float*)d_in[2],
        (const float*)d_in[3], (const float*)d_in[4],
        (const float*)d_in[5], (const float*)d_in[6],
        (const float*)d_in[7], (const float*)d_in[8],
        (const float*)d_in[9], (const float*)d_in[10],
        (float*)d_out);
}